// Round 24
// baseline (186.583 us; speedup 1.0000x reference)
//
#include <hip/hip_runtime.h>

#define DMODEL 1024
#define NEXP   32
#define FDIM   512
#define TOPK   4

#define MT1   256   // gemm1 token tile
#define MT2   128   // gemm2 token tile
#define BK    64    // k per stage (2 MFMA k-slices)
#define RTB   8     // tokens per routing block
#define NBORD 64    // blocks for hist/scatter phases

using short8 = __attribute__((ext_vector_type(8))) short;
using f32x4  = __attribute__((ext_vector_type(4))) float;

#define AS1 __attribute__((address_space(1)))
#define AS3 __attribute__((address_space(3)))
__device__ __forceinline__ void gload_lds16(const void* g, void* l) {
    __builtin_amdgcn_global_load_lds((const AS1 unsigned int*)g, (AS3 unsigned int*)l, 16, 0, 0);
}

__device__ __forceinline__ unsigned short f2b(float f) {
    unsigned int u = __float_as_uint(f);
    unsigned int r = (u + 0x7FFFu + ((u >> 16) & 1u)) >> 16;   // RNE bf16
    return (unsigned short)r;
}
__device__ __forceinline__ float b2f(unsigned short u) {
    return __uint_as_float((unsigned int)u << 16);
}

// ------- phase A: gates + top-4 -> sel arrays (LDS-staged x) + x->bf16 -------
__global__ __launch_bounds__(256) void route_a(
    const float* __restrict__ x, const float* __restrict__ esel,
    unsigned short* __restrict__ xb,
    unsigned int* __restrict__ sel_e, float* __restrict__ sel_g, int ntok)
{
    int tile0 = blockIdx.x * RTB;
    int tid = threadIdx.x;

    __shared__ float xs[RTB][DMODEL];   // 32 KB
    __shared__ float gs[RTB][NEXP];     // 1 KB

    {
        const float4* src = (const float4*)(x + (size_t)tile0 * DMODEL);
        float4* dst = (float4*)&xs[0][0];
        int navail = min(RTB, ntok - tile0) * (DMODEL / 4);
        for (int i = tid; i < RTB * (DMODEL / 4); i += 256)
            dst[i] = src[i < navail ? i : 0];
    }
    __syncthreads();

    int e = tid >> 3, sub = tid & 7;
    float4 acc0 = {0,0,0,0}, acc1 = {0,0,0,0}, acc2 = {0,0,0,0}, acc3 = {0,0,0,0};
    float4 acc4 = {0,0,0,0}, acc5 = {0,0,0,0}, acc6 = {0,0,0,0}, acc7 = {0,0,0,0};
    const float* er = esel + (size_t)e * DMODEL + sub * 4;
    #pragma unroll 4
    for (int j = 0; j < DMODEL / 32; j++) {
        float4 ev = *(const float4*)(er + j * 32);
        int kk = sub * 4 + j * 32;
        float4 x0 = *(const float4*)(&xs[0][kk]);
        float4 x1 = *(const float4*)(&xs[1][kk]);
        float4 x2 = *(const float4*)(&xs[2][kk]);
        float4 x3 = *(const float4*)(&xs[3][kk]);
        float4 x4 = *(const float4*)(&xs[4][kk]);
        float4 x5 = *(const float4*)(&xs[5][kk]);
        float4 x6 = *(const float4*)(&xs[6][kk]);
        float4 x7 = *(const float4*)(&xs[7][kk]);
        acc0.x += ev.x*x0.x; acc0.y += ev.y*x0.y; acc0.z += ev.z*x0.z; acc0.w += ev.w*x0.w;
        acc1.x += ev.x*x1.x; acc1.y += ev.y*x1.y; acc1.z += ev.z*x1.z; acc1.w += ev.w*x1.w;
        acc2.x += ev.x*x2.x; acc2.y += ev.y*x2.y; acc2.z += ev.z*x2.z; acc2.w += ev.w*x2.w;
        acc3.x += ev.x*x3.x; acc3.y += ev.y*x3.y; acc3.z += ev.z*x3.z; acc3.w += ev.w*x3.w;
        acc4.x += ev.x*x4.x; acc4.y += ev.y*x4.y; acc4.z += ev.z*x4.z; acc4.w += ev.w*x4.w;
        acc5.x += ev.x*x5.x; acc5.y += ev.y*x5.y; acc5.z += ev.z*x5.z; acc5.w += ev.w*x5.w;
        acc6.x += ev.x*x6.x; acc6.y += ev.y*x6.y; acc6.z += ev.z*x6.z; acc6.w += ev.w*x6.w;
        acc7.x += ev.x*x7.x; acc7.y += ev.y*x7.y; acc7.z += ev.z*x7.z; acc7.w += ev.w*x7.w;
    }
    {
        float s[RTB] = {
            acc0.x+acc0.y+acc0.z+acc0.w, acc1.x+acc1.y+acc1.z+acc1.w,
            acc2.x+acc2.y+acc2.z+acc2.w, acc3.x+acc3.y+acc3.z+acc3.w,
            acc4.x+acc4.y+acc4.z+acc4.w, acc5.x+acc5.y+acc5.z+acc5.w,
            acc6.x+acc6.y+acc6.z+acc6.w, acc7.x+acc7.y+acc7.z+acc7.w };
        #pragma unroll
        for (int t = 0; t < RTB; t++) {
            float v = s[t];
            v += __shfl_xor(v, 1);
            v += __shfl_xor(v, 2);
            v += __shfl_xor(v, 4);
            if (sub == 0) gs[t][e] = 1.f / (1.f + expf(-v));
        }
    }
    __syncthreads();

    {
        int t = tid >> 5, e2 = tid & 31;
        int tok = tile0 + t;
        if (tok < ntok) {
            float v = gs[t][e2];
            #pragma unroll
            for (int r = 0; r < TOPK; r++) {
                float bv = v; int bi = e2;
                #pragma unroll
                for (int sft = 16; sft >= 1; sft >>= 1) {
                    float ov = __shfl_xor(bv, sft, 32);
                    int   oi = __shfl_xor(bi, sft, 32);
                    if (ov > bv || (ov == bv && oi < bi)) { bv = ov; bi = oi; }
                }
                if (e2 == bi) v = -1e30f;
                if (e2 == r) {
                    sel_e[(size_t)tok * TOPK + r] = (unsigned)bi;
                    sel_g[(size_t)tok * TOPK + r] = bv;
                }
            }
        }
    }

    {
        int navail = min(RTB, ntok - tile0) * (DMODEL / 4);
        ushort4* dst = (ushort4*)(xb + (size_t)tile0 * DMODEL);
        const float4* srcl = (const float4*)&xs[0][0];
        for (int i = tid; i < navail; i += 256) {
            float4 v = srcl[i];
            ushort4 o;
            o.x = f2b(v.x); o.y = f2b(v.y); o.z = f2b(v.z); o.w = f2b(v.w);
            dst[i] = o;
        }
    }
}

// ------- phase B1: per-block expert histogram -------
__global__ __launch_bounds__(256) void hist_k(
    const unsigned int* __restrict__ sel_e, int* __restrict__ ghist, int nsel)
{
    __shared__ int h[NEXP];
    int tid = threadIdx.x;
    if (tid < NEXP) h[tid] = 0;
    __syncthreads();
    int chunk = (nsel + gridDim.x - 1) / gridDim.x;
    int i0 = blockIdx.x * chunk, i1 = min(i0 + chunk, nsel);
    for (int i = i0 + tid; i < i1; i += 256)
        atomicAdd(&h[sel_e[i]], 1);
    __syncthreads();
    if (tid < NEXP) ghist[blockIdx.x * NEXP + tid] = h[tid];
}

// ------- phase B2: prefix + base + BOTH tile lists -------
__global__ __launch_bounds__(64) void scan2_k(
    const int* __restrict__ ghist, int* __restrict__ goff,
    int* __restrict__ counts, int* __restrict__ base,
    int* __restrict__ tiles1, int* __restrict__ tiles2,
    int* __restrict__ ntiles, int nb)
{
    int e = threadIdx.x;
    if (e < NEXP) {
        int s = 0;
        for (int b = 0; b < nb; b++) {
            goff[b * NEXP + e] = s;
            s += ghist[b * NEXP + e];
        }
        counts[e] = s;
    }
    __syncthreads();
    if (e == 0) {
        int s = 0, nt1 = 0, nt2 = 0;
        for (int e2 = 0; e2 < NEXP; e2++) {
            base[e2] = s;
            int c = counts[e2];
            for (int t0 = 0; t0 < c; t0 += MT1) tiles1[nt1++] = (e2 << 8) | (t0 / MT1);
            for (int t0 = 0; t0 < c; t0 += MT2) tiles2[nt2++] = (e2 << 8) | (t0 / MT2);
            s += c;
        }
        ntiles[0] = nt1;
        ntiles[1] = nt2;
    }
}

// ------- phase B3: scatter into lists -------
__global__ __launch_bounds__(256) void scat_k(
    const unsigned int* __restrict__ sel_e, const float* __restrict__ sel_g,
    const int* __restrict__ goff,
    int* __restrict__ tok_list, float* __restrict__ gate_list,
    unsigned int* __restrict__ slotinfo, int nsel, int ntok)
{
    __shared__ int c[NEXP];
    int tid = threadIdx.x;
    if (tid < NEXP) c[tid] = goff[blockIdx.x * NEXP + tid];
    __syncthreads();
    int chunk = (nsel + gridDim.x - 1) / gridDim.x;
    int i0 = blockIdx.x * chunk, i1 = min(i0 + chunk, nsel);
    for (int i = i0 + tid; i < i1; i += 256) {
        unsigned int e = sel_e[i];
        float g = sel_g[i];
        int pos = atomicAdd(&c[e], 1);
        tok_list [(size_t)e * ntok + pos] = i >> 2;
        gate_list[(size_t)e * ntok + pos] = g;
        slotinfo[i] = (e << 16) | (unsigned)pos;
    }
}

// ------- prep (fused, VECTORIZED): transpose+convert src[e][R][C] -> dst[e][C][R] bf16 -------
__global__ __launch_bounds__(256) void prep_t2(
    const float* __restrict__ keys, const float* __restrict__ values,
    unsigned short* __restrict__ kt, unsigned short* __restrict__ vt)
{
    __shared__ float tile[64][65];
    int which = blockIdx.y;                          // 0: keys, 1: values
    int R = which ? FDIM : DMODEL;
    int C = which ? DMODEL : FDIM;
    const float* src = which ? values : keys;
    unsigned short* dst = which ? vt : kt;
    int e = blockIdx.z;
    int ctiles = C >> 6;
    int flat = blockIdx.x;                           // (R/64)*(C/64) = 128 both
    int cx = flat % ctiles, ry = flat / ctiles;
    int r0 = ry * 64, c0 = cx * 64;
    const float* s = src + (size_t)e * R * C;
    unsigned short* d = dst + (size_t)e * R * C;
    int tid = threadIdx.x;

    // load: float4 per lane, 4 iterations cover 64x64
    #pragma unroll
    for (int it = 0; it < 4; it++) {
        int lin = it * 1024 + tid * 4;
        int rr = lin >> 6, cc = lin & 63;
        float4 v = *(const float4*)(s + (size_t)(r0 + rr) * C + c0 + cc);
        tile[rr][cc]     = v.x;
        tile[rr][cc + 1] = v.y;
        tile[rr][cc + 2] = v.z;
        tile[rr][cc + 3] = v.w;
    }
    __syncthreads();
    // store: ushort4 per lane (dst row c0+wr, cols r0+wc..wc+3), 4 iterations
    #pragma unroll
    for (int it = 0; it < 4; it++) {
        int lin = it * 1024 + tid * 4;
        int wr = lin >> 6, wc = lin & 63;
        ushort4 o;
        o.x = f2b(tile[wc][wr]);
        o.y = f2b(tile[wc + 1][wr]);
        o.z = f2b(tile[wc + 2][wr]);
        o.w = f2b(tile[wc + 3][wr]);
        *(ushort4*)(d + (size_t)(c0 + wr) * R + r0 + wc) = o;
    }
}

// ---- GEMM1: hs = relu(x . K_e)*gate  (256x256, 8 waves, counted-vmcnt dbuf) ----
__global__ __launch_bounds__(512, 2) void gemm1_k(
    const unsigned short* __restrict__ xb,
    const unsigned short* __restrict__ kt,   // [E][512 f][1024 d]
    const int* __restrict__ counts, const int* __restrict__ base,
    const int* __restrict__ tiles, const int* __restrict__ ntiles,
    const int* __restrict__ tok_list, const float* __restrict__ gate_list,
    unsigned short* __restrict__ hs, int ntok)
{
    int ti = blockIdx.x;
    if (ti >= ntiles[0]) return;
    int code = tiles[ti];
    int e = code >> 8, t0 = (code & 255) * MT1;
    int cnt  = counts[e];
    int f0   = blockIdx.y * 256;             // FDIM/256 = 2 tiles
    int live = min(MT1, cnt - t0);

    __shared__ unsigned short Xs[2][MT1 * BK];   // 2 x 32 KB
    __shared__ unsigned short Ks[2][256 * BK];   // 2 x 32 KB
    __shared__ int   toks[MT1];
    __shared__ float gts[MT1];

    int tid = threadIdx.x, lane = tid & 63, wid = tid >> 6;   // 8 waves
    int wr = wid >> 2, wc = wid & 3;                          // 2M x 4N
    int lr = lane & 15, lg = lane >> 4;

    if (tid < MT1) {
        bool lv = tid < live;
        toks[tid] = lv ? tok_list [(size_t)e * ntok + t0 + tid] : 0;
        gts[tid]  = lv ? gate_list[(size_t)e * ntok + t0 + tid] : 0.f;
    }
    __syncthreads();

    int lrow = lane >> 3;
    int scol = ((lane & 7) ^ lrow) * 8;          // pre-swizzled ushort col
    const unsigned short* ke = kt + (size_t)e * FDIM * DMODEL + (size_t)f0 * DMODEL;
    const unsigned short* sx[4];
    const unsigned short* sk[4];
    int dofs[4];
    #pragma unroll
    for (int j = 0; j < 4; j++) {
        int ch = 4 * wid + j;
        int row = ch * 8 + lrow;
        sx[j] = xb + (size_t)toks[row] * DMODEL + scol;
        sk[j] = ke + (size_t)row * DMODEL + scol;
        dofs[j] = ch * 512;
    }

    f32x4 acc[8][4];
    #pragma unroll
    for (int m = 0; m < 8; m++)
        #pragma unroll
        for (int n = 0; n < 4; n++)
            acc[m][n] = (f32x4){0.f, 0.f, 0.f, 0.f};

    #pragma unroll
    for (int j = 0; j < 4; j++) {
        gload_lds16(sx[j], &Xs[0][dofs[j]]);
        gload_lds16(sk[j], &Ks[0][dofs[j]]);
    }

    int cur = 0;
    const int NKT = DMODEL / BK;           // 16
    for (int t = 0; t < NKT; t++) {
        bool more = (t + 1) < NKT;
        if (more) {
            int k1 = (t + 1) * BK;
            #pragma unroll
            for (int j = 0; j < 4; j++) {
                gload_lds16(sx[j] + k1, &Xs[cur ^ 1][dofs[j]]);
                gload_lds16(sk[j] + k1, &Ks[cur ^ 1][dofs[j]]);
            }
            asm volatile("s_waitcnt vmcnt(8)" ::: "memory");
        } else {
            asm volatile("s_waitcnt vmcnt(0)" ::: "memory");
        }
        __builtin_amdgcn_s_barrier();
        __builtin_amdgcn_sched_barrier(0);
        const unsigned short* Xc = Xs[cur];
        const unsigned short* Kc = Ks[cur];
        #pragma unroll
        for (int ks = 0; ks < 2; ks++) {
            short8 a[8];
            #pragma unroll
            for (int m = 0; m < 8; m++) {
                int row = wr * 128 + m * 16 + lr;
                a[m] = *(const short8*)(Xc + row * BK + (((ks * 4 + lg) ^ (lr & 7)) * 8));
            }
            #pragma unroll
            for (int n = 0; n < 4; n++) {
                int row = wc * 64 + n * 16 + lr;
                short8 b = *(const short8*)(Kc + row * BK + (((ks * 4 + lg) ^ (lr & 7)) * 8));
                #pragma unroll
                for (int m = 0; m < 8; m++)
                    acc[m][n] = __builtin_amdgcn_mfma_f32_16x16x32_bf16(a[m], b, acc[m][n], 0, 0, 0);
            }
        }
        __builtin_amdgcn_sched_barrier(0);
        asm volatile("s_waitcnt lgkmcnt(0)" ::: "memory");
        __builtin_amdgcn_s_barrier();
        cur ^= 1;
    }

    int hb = base[e] + t0;
    #pragma unroll
    for (int m = 0; m < 8; m++) {
        #pragma unroll
        for (int n = 0; n < 4; n++) {
            int col = f0 + wc * 64 + n * 16 + lr;
            #pragma unroll
            for (int r = 0; r < 4; r++) {
                int row = wr * 128 + m * 16 + lg * 4 + r;
                if (row < live)
                    hs[(size_t)(hb + row) * FDIM + col] = f2b(fmaxf(acc[m][n][r], 0.f) * gts[row]);
            }
        }
    }
}

// ---- GEMM2: ys(bf16) = hs . V_e  (128x128, 4 waves, counted-vmcnt dbuf) ----
__global__ __launch_bounds__(256) void gemm2_k(
    const unsigned short* __restrict__ hs,
    const unsigned short* __restrict__ vt,   // [E][1024 v][512 f]
    const int* __restrict__ counts, const int* __restrict__ base,
    const int* __restrict__ tiles2, const int* __restrict__ ntiles,
    unsigned short* __restrict__ ys)
{
    int ti = blockIdx.x;
    if (ti >= ntiles[1]) return;
    int code = tiles2[ti];
    int e = code >> 8, t0 = (code & 255) * MT2;
    int cnt  = counts[e];
    int v0   = blockIdx.y * 128;             // DMODEL/128 = 8 tiles
    int live = min(MT2, cnt - t0);
    int hb   = base[e] + t0;

    __shared__ unsigned short Hs[2][MT2 * BK];   // 2 x 16 KB
    __shared__ unsigned short Vs[2][128 * BK];   // 2 x 16 KB

    int tid = threadIdx.x, lane = tid & 63, w = tid >> 6;
    int lr = lane & 15, lg = lane >> 4;

    int lrow = lane >> 3;
    int scol = ((lane & 7) ^ lrow) * 8;
    const unsigned short* he = hs + (size_t)hb * FDIM;
    const unsigned short* ve = vt + (size_t)e * DMODEL * FDIM + (size_t)v0 * FDIM;
    const unsigned short* sh[4];
    const unsigned short* sv[4];
    int dofs[4];
    #pragma unroll
    for (int j = 0; j < 4; j++) {
        int ch = 4 * w + j;
        int row = ch * 8 + lrow;
        sh[j] = he + (size_t)row * FDIM + scol;      // may over-read slack rows
        sv[j] = ve + (size_t)row * FDIM + scol;
        dofs[j] = ch * 512;
    }

    f32x4 acc[8][2];
    #pragma unroll
    for (int m = 0; m < 8; m++)
        #pragma unroll
        for (int n = 0; n < 2; n++)
            acc[m][n] = (f32x4){0.f, 0.f, 0.f, 0.f};

    #pragma unroll
    for (int j = 0; j < 4; j++) {
        gload_lds16(sh[j], &Hs[0][dofs[j]]);
        gload_lds16(sv[j], &Vs[0][dofs[j]]);
    }

    int cur = 0;
    const int NKT = FDIM / BK;             // 8
    for (int t = 0; t < NKT; t++) {
        bool more = (t + 1) < NKT;
        if (more) {
            int k1 = (t + 1) * BK;
            #pragma unroll
            for (int j = 0; j < 4; j++) {
                gload_lds16(sh[j] + k1, &Hs[cur ^ 1][dofs[j]]);
                gload_lds16(sv[j] + k1, &Vs[cur ^ 1][dofs[j]]);
            }
            asm volatile("s_waitcnt vmcnt(8)" ::: "memory");
        } else {
            asm volatile("s_waitcnt vmcnt(0)" ::: "memory");
        }
        __builtin_amdgcn_s_barrier();
        __builtin_amdgcn_sched_barrier(0);
        const unsigned short* Hc = Hs[cur];
        const unsigned short* Vc = Vs[cur];
        #pragma unroll
        for (int ks = 0; ks < 2; ks++) {
            short8 a[8];
            #pragma unroll
            for (int m = 0; m < 8; m++) {
                int row = m * 16 + lr;
                a[m] = *(const short8*)(Hc + row * BK + (((ks * 4 + lg) ^ (lr & 7)) * 8));
            }
            #pragma unroll
            for (int n = 0; n < 2; n++) {
                int row = w * 32 + n * 16 + lr;
                short8 b = *(const short8*)(Vc + row * BK + (((ks * 4 + lg) ^ (lr & 7)) * 8));
                #pragma unroll
                for (int m = 0; m < 8; m++)
                    acc[m][n] = __builtin_amdgcn_mfma_f32_16x16x32_bf16(a[m], b, acc[m][n], 0, 0, 0);
            }
        }
        __builtin_amdgcn_sched_barrier(0);
        asm volatile("s_waitcnt lgkmcnt(0)" ::: "memory");
        __builtin_amdgcn_s_barrier();
        cur ^= 1;
    }

    #pragma unroll
    for (int m = 0; m < 8; m++) {
        #pragma unroll
        for (int n = 0; n < 2; n++) {
            int col = v0 + w * 32 + n * 16 + lr;
            #pragma unroll
            for (int r = 0; r < 4; r++) {
                int row = m * 16 + lg * 4 + r;
                if (row < live)
                    ys[(size_t)(hb + row) * DMODEL + col] = f2b(acc[m][n][r]);
            }
        }
    }
}

// ------- combine -------
__global__ __launch_bounds__(256) void combine_k(
    const unsigned short* __restrict__ ys, const unsigned int* __restrict__ slotinfo,
    const int* __restrict__ base, float* __restrict__ out)
{
    int tok = blockIdx.x;
    unsigned int s0 = slotinfo[(size_t)tok * TOPK + 0];
    unsigned int s1 = slotinfo[(size_t)tok * TOPK + 1];
    unsigned int s2 = slotinfo[(size_t)tok * TOPK + 2];
    unsigned int s3 = slotinfo[(size_t)tok * TOPK + 3];
    const ushort4* y0 = (const ushort4*)(ys + (size_t)(base[s0 >> 16] + (s0 & 0xFFFF)) * DMODEL);
    const ushort4* y1 = (const ushort4*)(ys + (size_t)(base[s1 >> 16] + (s1 & 0xFFFF)) * DMODEL);
    const ushort4* y2 = (const ushort4*)(ys + (size_t)(base[s2 >> 16] + (s2 & 0xFFFF)) * DMODEL);
    const ushort4* y3 = (const ushort4*)(ys + (size_t)(base[s3 >> 16] + (s3 & 0xFFFF)) * DMODEL);
    int i = threadIdx.x;
    ushort4 a = y0[i], b = y1[i], c = y2[i], d = y3[i];
    float4 o;
    o.x = b2f(a.x) + b2f(b.x) + b2f(c.x) + b2f(d.x);
    o.y = b2f(a.y) + b2f(b.y) + b2f(c.y) + b2f(d.y);
    o.z = b2f(a.z) + b2f(b.z) + b2f(c.z) + b2f(d.z);
    o.w = b2f(a.w) + b2f(b.w) + b2f(c.w) + b2f(d.w);
    ((float4*)(out + (size_t)tok * DMODEL))[i] = o;
}

// ---------------- fp32 fallback ----------------
#define BTF 16
__global__ __launch_bounds__(256) void expert_k(
    const float* __restrict__ x, const float* __restrict__ keys,
    const float* __restrict__ values, const int* __restrict__ counts,
    const int* __restrict__ tok_list, const float* __restrict__ gate_list,
    float* __restrict__ out, int ntok)
{
    int e   = blockIdx.y;
    int cnt = counts[e];
    int t0  = blockIdx.x * BTF;
    if (t0 >= cnt) return;
    int nt = (cnt - t0 < BTF) ? (cnt - t0) : BTF;

    __shared__ float xs[BTF][DMODEL];
    __shared__ float hsl[BTF][FDIM];
    __shared__ int   toks[BTF];
    __shared__ float gts[BTF];

    if (threadIdx.x < BTF) {
        int t = threadIdx.x;
        bool live = (t < nt);
        toks[t] = live ? tok_list [(size_t)e * ntok + t0 + t] : 0;
        gts[t]  = live ? gate_list[(size_t)e * ntok + t0 + t] : 0.f;
    }
    __syncthreads();
    for (int i = threadIdx.x; i < BTF * (DMODEL / 4); i += 256) {
        int r = i >> 8, c = i & 255;
        ((float4*)xs[r])[c] = ((const float4*)(x + (size_t)toks[r] * DMODEL))[c];
    }
    __syncthreads();

    {
        int f = threadIdx.x * 2;
        float acc0[BTF], acc1[BTF];
        #pragma unroll
        for (int t = 0; t < BTF; t++) { acc0[t] = 0.f; acc1[t] = 0.f; }
        const float* kp = keys + (size_t)e * DMODEL * FDIM + f;
        for (int k = 0; k < DMODEL; k += 4) {
            const float* kr = kp + (size_t)k * FDIM;
            float2 kv0 = *(const float2*)(kr);
            float2 kv1 = *(const float2*)(kr + FDIM);
            float2 kv2 = *(const float2*)(kr + 2 * FDIM);
            float2 kv3 = *(const float2*)(kr + 3 * FDIM);
            #pragma unroll
            for (int t = 0; t < BTF; t++) {
                float4 xv = *(const float4*)(&xs[t][k]);
                acc0[t] += xv.x * kv0.x + xv.y * kv1.x + xv.z * kv2.x + xv.w * kv3.x;
                acc1[t] += xv.x * kv0.y + xv.y * kv1.y + xv.z * kv2.y + xv.w * kv3.y;
            }
        }
        #pragma unroll
        for (int t = 0; t < BTF; t++) {
            float g = gts[t];
            hsl[t][f]     = fmaxf(acc0[t], 0.f) * g;
            hsl[t][f + 1] = fmaxf(acc1[t], 0.f) * g;
        }
    }
    __syncthreads();

    {
        int v = threadIdx.x * 4;
        float acc[BTF][4];
        #pragma unroll
        for (int t = 0; t < BTF; t++) { acc[t][0]=0.f; acc[t][1]=0.f; acc[t][2]=0.f; acc[t][3]=0.f; }
        const float* vp = values + (size_t)e * FDIM * DMODEL + v;
        for (int k = 0; k < FDIM; k += 2) {
            float4 va0 = *(const float4*)(vp + (size_t)k * DMODEL);
            float4 va1 = *(const float4*)(vp + (size_t)(k + 1) * DMODEL);
            #pragma unroll
            for (int t = 0; t < BTF; t++) {
                float2 hv = *(const float2*)(&hsl[t][k]);
                acc[t][0] += hv.x * va0.x + hv.y * va1.x;
                acc[t][1] += hv.x * va0.y + hv.y * va1.y;
                acc[t][2] += hv.x * va0.z + hv.y * va1.z;
                acc[t][3] += hv.x * va0.w + hv.y * va1.w;
            }
        }
        #pragma unroll
        for (int t = 0; t < BTF; t++) {
            if (t < nt) {
                float* orow = out + (size_t)toks[t] * DMODEL + v;
                atomicAdd(orow + 0, acc[t][0]);
                atomicAdd(orow + 1, acc[t][1]);
                atomicAdd(orow + 2, acc[t][2]);
                atomicAdd(orow + 3, acc[t][3]);
            }
        }
    }
}

extern "C" void kernel_launch(void* const* d_in, const int* in_sizes, int n_in,
                              void* d_out, int out_size, void* d_ws, size_t ws_size,
                              hipStream_t stream) {
    const float* x      = (const float*)d_in[0];
    const float* esel   = (const float*)d_in[1];
    const float* keys   = (const float*)d_in[2];
    const float* values = (const float*)d_in[3];
    float* out = (float*)d_out;
    int ntok = in_sizes[0] / DMODEL;

    // workspace layout
    const size_t OFF_BASE  = 512;
    const size_t OFF_NT    = 1024;        // int[2]
    const size_t OFF_TILE1 = 2048;
    const size_t OFF_TILE2 = 8 << 10;
    const size_t OFF_HIST  = 16 << 10;
    const size_t OFF_GOFF  = 32 << 10;
    const size_t OFF_SLOT  = 64 << 10;
    const size_t OFF_SELE  = 128 << 10;
    const size_t OFF_SELG  = 192 << 10;
    const size_t OFF_TOK   = 256 << 10;
    const size_t OFF_GATE  = 1ull << 20;
    const size_t OFF_XB    = 2ull << 20;
    const size_t OFF_KT    = 12ull << 20;
    const size_t OFF_VT    = 46ull << 20;
    const size_t OFF_HS    = 80ull << 20;
    const size_t OFF_YS    = 98ull << 20;
    const size_t NEED      = OFF_YS + (size_t)ntok * TOPK * DMODEL * sizeof(float) + (1 << 20);

    int*      counts    = (int*)d_ws;
    int*      ebase     = (int*)((char*)d_ws + OFF_BASE);
    int*      ntiles    = (int*)((char*)d_ws + OFF_NT);
    int*      tiles1    = (int*)((char*)d_ws + OFF_TILE1);
    int*      tiles2    = (int*)((char*)d_ws + OFF_TILE2);
    int*      ghist     = (int*)((char*)d_ws + OFF_HIST);
    int*      goff      = (int*)((char*)d_ws + OFF_GOFF);
    unsigned* slotinfo  = (unsigned*)((char*)d_ws + OFF_SLOT);
    unsigned* sel_e     = (unsigned*)((char*)d_ws + OFF_SELE);
    float*    sel_g     = (float*)((char*)d_ws + OFF_SELG);
    int*      tok_list  = (int*)((char*)d_ws + OFF_TOK);
    float*    gate_list = (float*)((char*)d_ws + OFF_GATE);
    unsigned short* xb  = (unsigned short*)((char*)d_ws + OFF_XB);

    int nsel = ntok * TOPK;
    int rblocks = (ntok + RTB - 1) / RTB;
    route_a<<<rblocks, 256, 0, stream>>>(x, esel, xb, sel_e, sel_g, ntok);
    hist_k<<<NBORD, 256, 0, stream>>>(sel_e, ghist, nsel);
    scan2_k<<<1, 64, 0, stream>>>(ghist, goff, counts, ebase, tiles1, tiles2,
                                  ntiles, NBORD);
    scat_k<<<NBORD, 256, 0, stream>>>(sel_e, sel_g, goff, tok_list, gate_list,
                                      slotinfo, nsel, ntok);

    if (ws_size >= NEED) {
        unsigned short* kt = (unsigned short*)((char*)d_ws + OFF_KT);
        unsigned short* vt = (unsigned short*)((char*)d_ws + OFF_VT);
        unsigned short* hs = (unsigned short*)((char*)d_ws + OFF_HS);
        unsigned short* ys = (unsigned short*)((char*)d_ws + OFF_YS);

        prep_t2<<<dim3(128, 2, NEXP), 256, 0, stream>>>(keys, values, kt, vt);

        int maxt1 = (nsel + MT1 - 1) / MT1 + NEXP;
        int maxt2 = (nsel + MT2 - 1) / MT2 + NEXP;
        gemm1_k<<<dim3(maxt1, FDIM / 256), 512, 0, stream>>>(
            xb, kt, counts, ebase, tiles1, ntiles, tok_list, gate_list, hs, ntok);
        gemm2_k<<<dim3(maxt2, DMODEL / 128), 256, 0, stream>>>(
            hs, vt, counts, ebase, tiles2, ntiles, ys);
        combine_k<<<ntok, 256, 0, stream>>>(ys, slotinfo, ebase, out);
    } else {
        hipMemsetAsync(out, 0, (size_t)out_size * sizeof(float), stream);
        int ntiles2f = (ntok + BTF - 1) / BTF;
        expert_k<<<dim3(ntiles2f, NEXP), 256, 0, stream>>>(
            x, keys, values, counts, tok_list, gate_list, out, ntok);
    }
}

// Round 26
// 164.935 us; speedup vs baseline: 1.1313x; 1.1313x over previous
//
#include <hip/hip_runtime.h>

#define DMODEL 1024
#define NEXP   32
#define FDIM   512
#define TOPK   4

#define MT1   256   // gemm1 token tile
#define MT2   128   // gemm2 token tile
#define BK    64    // k per stage (2 MFMA k-slices)
#define RTB   8     // tokens per routing block
#define NBORD 64    // blocks for hist/scatter phases

using short8 = __attribute__((ext_vector_type(8))) short;
using f32x4  = __attribute__((ext_vector_type(4))) float;

#define AS1 __attribute__((address_space(1)))
#define AS3 __attribute__((address_space(3)))
__device__ __forceinline__ void gload_lds16(const void* g, void* l) {
    __builtin_amdgcn_global_load_lds((const AS1 unsigned int*)g, (AS3 unsigned int*)l, 16, 0, 0);
}

__device__ __forceinline__ unsigned short f2b(float f) {
    unsigned int u = __float_as_uint(f);
    unsigned int r = (u + 0x7FFFu + ((u >> 16) & 1u)) >> 16;   // RNE bf16
    return (unsigned short)r;
}
__device__ __forceinline__ float b2f(unsigned short u) {
    return __uint_as_float((unsigned int)u << 16);
}

// ------- FUSED front: routing blocks + weight-transpose blocks in one launch -------
__global__ __launch_bounds__(256) void front_k(
    const float* __restrict__ x, const float* __restrict__ esel,
    const float* __restrict__ keys, const float* __restrict__ values,
    unsigned short* __restrict__ xb,
    unsigned short* __restrict__ kt, unsigned short* __restrict__ vt,
    unsigned int* __restrict__ sel_e, float* __restrict__ sel_g,
    int ntok, int rblocks)
{
    __shared__ float smem[RTB * DMODEL + RTB * NEXP];   // 33 KB (union)
    int bid = blockIdx.x;
    int tid = threadIdx.x;

    if (bid < rblocks) {
        // ---------------- routing body ----------------
        float (*xs)[DMODEL] = (float(*)[DMODEL])smem;
        float (*gs)[NEXP]   = (float(*)[NEXP])(smem + RTB * DMODEL);
        int tile0 = bid * RTB;

        {
            const float4* src = (const float4*)(x + (size_t)tile0 * DMODEL);
            float4* dst = (float4*)&xs[0][0];
            int navail = min(RTB, ntok - tile0) * (DMODEL / 4);
            for (int i = tid; i < RTB * (DMODEL / 4); i += 256)
                dst[i] = src[i < navail ? i : 0];
        }
        __syncthreads();

        int e = tid >> 3, sub = tid & 7;
        float4 acc0 = {0,0,0,0}, acc1 = {0,0,0,0}, acc2 = {0,0,0,0}, acc3 = {0,0,0,0};
        float4 acc4 = {0,0,0,0}, acc5 = {0,0,0,0}, acc6 = {0,0,0,0}, acc7 = {0,0,0,0};
        const float* er = esel + (size_t)e * DMODEL + sub * 4;
        #pragma unroll 4
        for (int j = 0; j < DMODEL / 32; j++) {
            float4 ev = *(const float4*)(er + j * 32);
            int kk = sub * 4 + j * 32;
            float4 x0 = *(const float4*)(&xs[0][kk]);
            float4 x1 = *(const float4*)(&xs[1][kk]);
            float4 x2 = *(const float4*)(&xs[2][kk]);
            float4 x3 = *(const float4*)(&xs[3][kk]);
            float4 x4 = *(const float4*)(&xs[4][kk]);
            float4 x5 = *(const float4*)(&xs[5][kk]);
            float4 x6 = *(const float4*)(&xs[6][kk]);
            float4 x7 = *(const float4*)(&xs[7][kk]);
            acc0.x += ev.x*x0.x; acc0.y += ev.y*x0.y; acc0.z += ev.z*x0.z; acc0.w += ev.w*x0.w;
            acc1.x += ev.x*x1.x; acc1.y += ev.y*x1.y; acc1.z += ev.z*x1.z; acc1.w += ev.w*x1.w;
            acc2.x += ev.x*x2.x; acc2.y += ev.y*x2.y; acc2.z += ev.z*x2.z; acc2.w += ev.w*x2.w;
            acc3.x += ev.x*x3.x; acc3.y += ev.y*x3.y; acc3.z += ev.z*x3.z; acc3.w += ev.w*x3.w;
            acc4.x += ev.x*x4.x; acc4.y += ev.y*x4.y; acc4.z += ev.z*x4.z; acc4.w += ev.w*x4.w;
            acc5.x += ev.x*x5.x; acc5.y += ev.y*x5.y; acc5.z += ev.z*x5.z; acc5.w += ev.w*x5.w;
            acc6.x += ev.x*x6.x; acc6.y += ev.y*x6.y; acc6.z += ev.z*x6.z; acc6.w += ev.w*x6.w;
            acc7.x += ev.x*x7.x; acc7.y += ev.y*x7.y; acc7.z += ev.z*x7.z; acc7.w += ev.w*x7.w;
        }
        {
            float s[RTB] = {
                acc0.x+acc0.y+acc0.z+acc0.w, acc1.x+acc1.y+acc1.z+acc1.w,
                acc2.x+acc2.y+acc2.z+acc2.w, acc3.x+acc3.y+acc3.z+acc3.w,
                acc4.x+acc4.y+acc4.z+acc4.w, acc5.x+acc5.y+acc5.z+acc5.w,
                acc6.x+acc6.y+acc6.z+acc6.w, acc7.x+acc7.y+acc7.z+acc7.w };
            #pragma unroll
            for (int t = 0; t < RTB; t++) {
                float v = s[t];
                v += __shfl_xor(v, 1);
                v += __shfl_xor(v, 2);
                v += __shfl_xor(v, 4);
                if (sub == 0) gs[t][e] = 1.f / (1.f + expf(-v));
            }
        }
        __syncthreads();

        {
            int t = tid >> 5, e2 = tid & 31;
            int tok = tile0 + t;
            if (tok < ntok) {
                float v = gs[t][e2];
                #pragma unroll
                for (int r = 0; r < TOPK; r++) {
                    float bv = v; int bi = e2;
                    #pragma unroll
                    for (int sft = 16; sft >= 1; sft >>= 1) {
                        float ov = __shfl_xor(bv, sft, 32);
                        int   oi = __shfl_xor(bi, sft, 32);
                        if (ov > bv || (ov == bv && oi < bi)) { bv = ov; bi = oi; }
                    }
                    if (e2 == bi) v = -1e30f;
                    if (e2 == r) {
                        sel_e[(size_t)tok * TOPK + r] = (unsigned)bi;
                        sel_g[(size_t)tok * TOPK + r] = bv;
                    }
                }
            }
        }

        {
            int navail = min(RTB, ntok - tile0) * (DMODEL / 4);
            ushort4* dst = (ushort4*)(xb + (size_t)tile0 * DMODEL);
            const float4* srcl = (const float4*)&xs[0][0];
            for (int i = tid; i < navail; i += 256) {
                float4 v = srcl[i];
                ushort4 o;
                o.x = f2b(v.x); o.y = f2b(v.y); o.z = f2b(v.z); o.w = f2b(v.w);
                dst[i] = o;
            }
        }
    } else {
        // ---------------- prep body (vectorized transpose) ----------------
        float (*tile)[65] = (float(*)[65])smem;     // 16.6 KB of the union
        int pid = bid - rblocks;                    // 0..8191
        int e     = pid >> 8;                       // 0..31
        int rem   = pid & 255;
        int which = rem >> 7;                       // 0: keys, 1: values
        int flat  = rem & 127;                      // 0..127
        int R = which ? FDIM : DMODEL;
        int C = which ? DMODEL : FDIM;
        const float* src = which ? values : keys;
        unsigned short* dst = which ? vt : kt;
        int ctiles = C >> 6;
        int cx = flat % ctiles, ry = flat / ctiles;
        int r0 = ry * 64, c0 = cx * 64;
        const float* s = src + (size_t)e * R * C;
        unsigned short* d = dst + (size_t)e * R * C;

        #pragma unroll
        for (int it = 0; it < 4; it++) {
            int lin = it * 1024 + tid * 4;
            int rr = lin >> 6, cc = lin & 63;
            float4 v = *(const float4*)(s + (size_t)(r0 + rr) * C + c0 + cc);
            tile[rr][cc]     = v.x;
            tile[rr][cc + 1] = v.y;
            tile[rr][cc + 2] = v.z;
            tile[rr][cc + 3] = v.w;
        }
        __syncthreads();
        #pragma unroll
        for (int it = 0; it < 4; it++) {
            int lin = it * 1024 + tid * 4;
            int wr = lin >> 6, wc = lin & 63;
            ushort4 o;
            o.x = f2b(tile[wc][wr]);
            o.y = f2b(tile[wc + 1][wr]);
            o.z = f2b(tile[wc + 2][wr]);
            o.w = f2b(tile[wc + 3][wr]);
            *(ushort4*)(d + (size_t)(c0 + wr) * R + r0 + wc) = o;
        }
    }
}

// ------- phase B1: per-block expert histogram -------
__global__ __launch_bounds__(256) void hist_k(
    const unsigned int* __restrict__ sel_e, int* __restrict__ ghist, int nsel)
{
    __shared__ int h[NEXP];
    int tid = threadIdx.x;
    if (tid < NEXP) h[tid] = 0;
    __syncthreads();
    int chunk = (nsel + gridDim.x - 1) / gridDim.x;
    int i0 = blockIdx.x * chunk, i1 = min(i0 + chunk, nsel);
    for (int i = i0 + tid; i < i1; i += 256)
        atomicAdd(&h[sel_e[i]], 1);
    __syncthreads();
    if (tid < NEXP) ghist[blockIdx.x * NEXP + tid] = h[tid];
}

// ------- phase B2: prefix + base + BOTH tile lists -------
__global__ __launch_bounds__(64) void scan2_k(
    const int* __restrict__ ghist, int* __restrict__ goff,
    int* __restrict__ counts, int* __restrict__ base,
    int* __restrict__ tiles1, int* __restrict__ tiles2,
    int* __restrict__ ntiles, int nb)
{
    int e = threadIdx.x;
    if (e < NEXP) {
        int s = 0;
        for (int b = 0; b < nb; b++) {
            goff[b * NEXP + e] = s;
            s += ghist[b * NEXP + e];
        }
        counts[e] = s;
    }
    __syncthreads();
    if (e == 0) {
        int s = 0, nt1 = 0, nt2 = 0;
        for (int e2 = 0; e2 < NEXP; e2++) {
            base[e2] = s;
            int c = counts[e2];
            for (int t0 = 0; t0 < c; t0 += MT1) tiles1[nt1++] = (e2 << 8) | (t0 / MT1);
            for (int t0 = 0; t0 < c; t0 += MT2) tiles2[nt2++] = (e2 << 8) | (t0 / MT2);
            s += c;
        }
        ntiles[0] = nt1;
        ntiles[1] = nt2;
    }
}

// ------- phase B3: scatter into lists -------
__global__ __launch_bounds__(256) void scat_k(
    const unsigned int* __restrict__ sel_e, const float* __restrict__ sel_g,
    const int* __restrict__ goff,
    int* __restrict__ tok_list, float* __restrict__ gate_list,
    unsigned int* __restrict__ slotinfo, int nsel, int ntok)
{
    __shared__ int c[NEXP];
    int tid = threadIdx.x;
    if (tid < NEXP) c[tid] = goff[blockIdx.x * NEXP + tid];
    __syncthreads();
    int chunk = (nsel + gridDim.x - 1) / gridDim.x;
    int i0 = blockIdx.x * chunk, i1 = min(i0 + chunk, nsel);
    for (int i = i0 + tid; i < i1; i += 256) {
        unsigned int e = sel_e[i];
        float g = sel_g[i];
        int pos = atomicAdd(&c[e], 1);
        tok_list [(size_t)e * ntok + pos] = i >> 2;
        gate_list[(size_t)e * ntok + pos] = g;
        slotinfo[i] = (e << 16) | (unsigned)pos;
    }
}

// ---- GEMM1: hs = relu(x . K_e)*gate  (256x256, 8 waves, counted-vmcnt dbuf) ----
__global__ __launch_bounds__(512, 2) void gemm1_k(
    const unsigned short* __restrict__ xb,
    const unsigned short* __restrict__ kt,   // [E][512 f][1024 d]
    const int* __restrict__ counts, const int* __restrict__ base,
    const int* __restrict__ tiles, const int* __restrict__ ntiles,
    const int* __restrict__ tok_list, const float* __restrict__ gate_list,
    unsigned short* __restrict__ hs, int ntok)
{
    int ti = blockIdx.x;
    if (ti >= ntiles[0]) return;
    int code = tiles[ti];
    int e = code >> 8, t0 = (code & 255) * MT1;
    int cnt  = counts[e];
    int f0   = blockIdx.y * 256;             // FDIM/256 = 2 tiles
    int live = min(MT1, cnt - t0);

    __shared__ unsigned short Xs[2][MT1 * BK];   // 2 x 32 KB
    __shared__ unsigned short Ks[2][256 * BK];   // 2 x 32 KB
    __shared__ int   toks[MT1];
    __shared__ float gts[MT1];

    int tid = threadIdx.x, lane = tid & 63, wid = tid >> 6;   // 8 waves
    int wr = wid >> 2, wc = wid & 3;                          // 2M x 4N
    int lr = lane & 15, lg = lane >> 4;

    if (tid < MT1) {
        bool lv = tid < live;
        toks[tid] = lv ? tok_list [(size_t)e * ntok + t0 + tid] : 0;
        gts[tid]  = lv ? gate_list[(size_t)e * ntok + t0 + tid] : 0.f;
    }
    __syncthreads();

    int lrow = lane >> 3;
    int scol = ((lane & 7) ^ lrow) * 8;          // pre-swizzled ushort col
    const unsigned short* ke = kt + (size_t)e * FDIM * DMODEL + (size_t)f0 * DMODEL;
    const unsigned short* sx[4];
    const unsigned short* sk[4];
    int dofs[4];
    #pragma unroll
    for (int j = 0; j < 4; j++) {
        int ch = 4 * wid + j;
        int row = ch * 8 + lrow;
        sx[j] = xb + (size_t)toks[row] * DMODEL + scol;
        sk[j] = ke + (size_t)row * DMODEL + scol;
        dofs[j] = ch * 512;
    }

    f32x4 acc[8][4];
    #pragma unroll
    for (int m = 0; m < 8; m++)
        #pragma unroll
        for (int n = 0; n < 4; n++)
            acc[m][n] = (f32x4){0.f, 0.f, 0.f, 0.f};

    #pragma unroll
    for (int j = 0; j < 4; j++) {
        gload_lds16(sx[j], &Xs[0][dofs[j]]);
        gload_lds16(sk[j], &Ks[0][dofs[j]]);
    }

    int cur = 0;
    const int NKT = DMODEL / BK;           // 16
    for (int t = 0; t < NKT; t++) {
        bool more = (t + 1) < NKT;
        if (more) {
            int k1 = (t + 1) * BK;
            #pragma unroll
            for (int j = 0; j < 4; j++) {
                gload_lds16(sx[j] + k1, &Xs[cur ^ 1][dofs[j]]);
                gload_lds16(sk[j] + k1, &Ks[cur ^ 1][dofs[j]]);
            }
            asm volatile("s_waitcnt vmcnt(8)" ::: "memory");
        } else {
            asm volatile("s_waitcnt vmcnt(0)" ::: "memory");
        }
        __builtin_amdgcn_s_barrier();
        __builtin_amdgcn_sched_barrier(0);
        const unsigned short* Xc = Xs[cur];
        const unsigned short* Kc = Ks[cur];
        #pragma unroll
        for (int ks = 0; ks < 2; ks++) {
            short8 a[8];
            #pragma unroll
            for (int m = 0; m < 8; m++) {
                int row = wr * 128 + m * 16 + lr;
                a[m] = *(const short8*)(Xc + row * BK + (((ks * 4 + lg) ^ (lr & 7)) * 8));
            }
            #pragma unroll
            for (int n = 0; n < 4; n++) {
                int row = wc * 64 + n * 16 + lr;
                short8 b = *(const short8*)(Kc + row * BK + (((ks * 4 + lg) ^ (lr & 7)) * 8));
                #pragma unroll
                for (int m = 0; m < 8; m++)
                    acc[m][n] = __builtin_amdgcn_mfma_f32_16x16x32_bf16(a[m], b, acc[m][n], 0, 0, 0);
            }
        }
        __builtin_amdgcn_sched_barrier(0);
        asm volatile("s_waitcnt lgkmcnt(0)" ::: "memory");
        __builtin_amdgcn_s_barrier();
        cur ^= 1;
    }

    int hb = base[e] + t0;
    #pragma unroll
    for (int m = 0; m < 8; m++) {
        #pragma unroll
        for (int n = 0; n < 4; n++) {
            int col = f0 + wc * 64 + n * 16 + lr;
            #pragma unroll
            for (int r = 0; r < 4; r++) {
                int row = wr * 128 + m * 16 + lg * 4 + r;
                if (row < live)
                    hs[(size_t)(hb + row) * FDIM + col] = f2b(fmaxf(acc[m][n][r], 0.f) * gts[row]);
            }
        }
    }
}

// ---- GEMM2: ys(bf16) = hs . V_e  (128x128, 4 waves, counted-vmcnt dbuf) ----
__global__ __launch_bounds__(256) void gemm2_k(
    const unsigned short* __restrict__ hs,
    const unsigned short* __restrict__ vt,   // [E][1024 v][512 f]
    const int* __restrict__ counts, const int* __restrict__ base,
    const int* __restrict__ tiles2, const int* __restrict__ ntiles,
    unsigned short* __restrict__ ys)
{
    int ti = blockIdx.x;
    if (ti >= ntiles[1]) return;
    int code = tiles2[ti];
    int e = code >> 8, t0 = (code & 255) * MT2;
    int cnt  = counts[e];
    int v0   = blockIdx.y * 128;             // DMODEL/128 = 8 tiles
    int live = min(MT2, cnt - t0);
    int hb   = base[e] + t0;

    __shared__ unsigned short Hs[2][MT2 * BK];   // 2 x 16 KB
    __shared__ unsigned short Vs[2][128 * BK];   // 2 x 16 KB

    int tid = threadIdx.x, lane = tid & 63, w = tid >> 6;
    int lr = lane & 15, lg = lane >> 4;

    int lrow = lane >> 3;
    int scol = ((lane & 7) ^ lrow) * 8;
    const unsigned short* he = hs + (size_t)hb * FDIM;
    const unsigned short* ve = vt + (size_t)e * DMODEL * FDIM + (size_t)v0 * FDIM;
    const unsigned short* sh[4];
    const unsigned short* sv[4];
    int dofs[4];
    #pragma unroll
    for (int j = 0; j < 4; j++) {
        int ch = 4 * w + j;
        int row = ch * 8 + lrow;
        sh[j] = he + (size_t)row * FDIM + scol;      // may over-read slack rows
        sv[j] = ve + (size_t)row * FDIM + scol;
        dofs[j] = ch * 512;
    }

    f32x4 acc[8][2];
    #pragma unroll
    for (int m = 0; m < 8; m++)
        #pragma unroll
        for (int n = 0; n < 2; n++)
            acc[m][n] = (f32x4){0.f, 0.f, 0.f, 0.f};

    #pragma unroll
    for (int j = 0; j < 4; j++) {
        gload_lds16(sh[j], &Hs[0][dofs[j]]);
        gload_lds16(sv[j], &Vs[0][dofs[j]]);
    }

    int cur = 0;
    const int NKT = FDIM / BK;             // 8
    for (int t = 0; t < NKT; t++) {
        bool more = (t + 1) < NKT;
        if (more) {
            int k1 = (t + 1) * BK;
            #pragma unroll
            for (int j = 0; j < 4; j++) {
                gload_lds16(sh[j] + k1, &Hs[cur ^ 1][dofs[j]]);
                gload_lds16(sv[j] + k1, &Vs[cur ^ 1][dofs[j]]);
            }
            asm volatile("s_waitcnt vmcnt(8)" ::: "memory");
        } else {
            asm volatile("s_waitcnt vmcnt(0)" ::: "memory");
        }
        __builtin_amdgcn_s_barrier();
        __builtin_amdgcn_sched_barrier(0);
        const unsigned short* Hc = Hs[cur];
        const unsigned short* Vc = Vs[cur];
        #pragma unroll
        for (int ks = 0; ks < 2; ks++) {
            short8 a[8];
            #pragma unroll
            for (int m = 0; m < 8; m++) {
                int row = m * 16 + lr;
                a[m] = *(const short8*)(Hc + row * BK + (((ks * 4 + lg) ^ (lr & 7)) * 8));
            }
            #pragma unroll
            for (int n = 0; n < 2; n++) {
                int row = w * 32 + n * 16 + lr;
                short8 b = *(const short8*)(Vc + row * BK + (((ks * 4 + lg) ^ (lr & 7)) * 8));
                #pragma unroll
                for (int m = 0; m < 8; m++)
                    acc[m][n] = __builtin_amdgcn_mfma_f32_16x16x32_bf16(a[m], b, acc[m][n], 0, 0, 0);
            }
        }
        __builtin_amdgcn_sched_barrier(0);
        asm volatile("s_waitcnt lgkmcnt(0)" ::: "memory");
        __builtin_amdgcn_s_barrier();
        cur ^= 1;
    }

    #pragma unroll
    for (int m = 0; m < 8; m++) {
        #pragma unroll
        for (int n = 0; n < 2; n++) {
            int col = v0 + w * 32 + n * 16 + lr;
            #pragma unroll
            for (int r = 0; r < 4; r++) {
                int row = m * 16 + lg * 4 + r;
                if (row < live)
                    ys[(size_t)(hb + row) * DMODEL + col] = f2b(acc[m][n][r]);
            }
        }
    }
}

// ------- combine -------
__global__ __launch_bounds__(256) void combine_k(
    const unsigned short* __restrict__ ys, const unsigned int* __restrict__ slotinfo,
    const int* __restrict__ base, float* __restrict__ out)
{
    int tok = blockIdx.x;
    unsigned int s0 = slotinfo[(size_t)tok * TOPK + 0];
    unsigned int s1 = slotinfo[(size_t)tok * TOPK + 1];
    unsigned int s2 = slotinfo[(size_t)tok * TOPK + 2];
    unsigned int s3 = slotinfo[(size_t)tok * TOPK + 3];
    const ushort4* y0 = (const ushort4*)(ys + (size_t)(base[s0 >> 16] + (s0 & 0xFFFF)) * DMODEL);
    const ushort4* y1 = (const ushort4*)(ys + (size_t)(base[s1 >> 16] + (s1 & 0xFFFF)) * DMODEL);
    const ushort4* y2 = (const ushort4*)(ys + (size_t)(base[s2 >> 16] + (s2 & 0xFFFF)) * DMODEL);
    const ushort4* y3 = (const ushort4*)(ys + (size_t)(base[s3 >> 16] + (s3 & 0xFFFF)) * DMODEL);
    int i = threadIdx.x;
    ushort4 a = y0[i], b = y1[i], c = y2[i], d = y3[i];
    float4 o;
    o.x = b2f(a.x) + b2f(b.x) + b2f(c.x) + b2f(d.x);
    o.y = b2f(a.y) + b2f(b.y) + b2f(c.y) + b2f(d.y);
    o.z = b2f(a.z) + b2f(b.z) + b2f(c.z) + b2f(d.z);
    o.w = b2f(a.w) + b2f(b.w) + b2f(c.w) + b2f(d.w);
    ((float4*)(out + (size_t)tok * DMODEL))[i] = o;
}

// ---------------- fp32 fallback ----------------
#define BTF 16
__global__ __launch_bounds__(256) void expert_k(
    const float* __restrict__ x, const float* __restrict__ keys,
    const float* __restrict__ values, const int* __restrict__ counts,
    const int* __restrict__ tok_list, const float* __restrict__ gate_list,
    float* __restrict__ out, int ntok)
{
    int e   = blockIdx.y;
    int cnt = counts[e];
    int t0  = blockIdx.x * BTF;
    if (t0 >= cnt) return;
    int nt = (cnt - t0 < BTF) ? (cnt - t0) : BTF;

    __shared__ float xs[BTF][DMODEL];
    __shared__ float hsl[BTF][FDIM];
    __shared__ int   toks[BTF];
    __shared__ float gts[BTF];

    if (threadIdx.x < BTF) {
        int t = threadIdx.x;
        bool live = (t < nt);
        toks[t] = live ? tok_list [(size_t)e * ntok + t0 + t] : 0;
        gts[t]  = live ? gate_list[(size_t)e * ntok + t0 + t] : 0.f;
    }
    __syncthreads();
    for (int i = threadIdx.x; i < BTF * (DMODEL / 4); i += 256) {
        int r = i >> 8, c = i & 255;
        ((float4*)xs[r])[c] = ((const float4*)(x + (size_t)toks[r] * DMODEL))[c];
    }
    __syncthreads();

    {
        int f = threadIdx.x * 2;
        float acc0[BTF], acc1[BTF];
        #pragma unroll
        for (int t = 0; t < BTF; t++) { acc0[t] = 0.f; acc1[t] = 0.f; }
        const float* kp = keys + (size_t)e * DMODEL * FDIM + f;
        for (int k = 0; k < DMODEL; k += 4) {
            const float* kr = kp + (size_t)k * FDIM;
            float2 kv0 = *(const float2*)(kr);
            float2 kv1 = *(const float2*)(kr + FDIM);
            float2 kv2 = *(const float2*)(kr + 2 * FDIM);
            float2 kv3 = *(const float2*)(kr + 3 * FDIM);
            #pragma unroll
            for (int t = 0; t < BTF; t++) {
                float4 xv = *(const float4*)(&xs[t][k]);
                acc0[t] += xv.x * kv0.x + xv.y * kv1.x + xv.z * kv2.x + xv.w * kv3.x;
                acc1[t] += xv.x * kv0.y + xv.y * kv1.y + xv.z * kv2.y + xv.w * kv3.y;
            }
        }
        #pragma unroll
        for (int t = 0; t < BTF; t++) {
            float g = gts[t];
            hsl[t][f]     = fmaxf(acc0[t], 0.f) * g;
            hsl[t][f + 1] = fmaxf(acc1[t], 0.f) * g;
        }
    }
    __syncthreads();

    {
        int v = threadIdx.x * 4;
        float acc[BTF][4];
        #pragma unroll
        for (int t = 0; t < BTF; t++) { acc[t][0]=0.f; acc[t][1]=0.f; acc[t][2]=0.f; acc[t][3]=0.f; }
        const float* vp = values + (size_t)e * FDIM * DMODEL + v;
        for (int k = 0; k < FDIM; k += 2) {
            float4 va0 = *(const float4*)(vp + (size_t)k * DMODEL);
            float4 va1 = *(const float4*)(vp + (size_t)(k + 1) * DMODEL);
            #pragma unroll
            for (int t = 0; t < BTF; t++) {
                float2 hv = *(const float2*)(&hsl[t][k]);
                acc[t][0] += hv.x * va0.x + hv.y * va1.x;
                acc[t][1] += hv.x * va0.y + hv.y * va1.y;
                acc[t][2] += hv.x * va0.z + hv.y * va1.z;
                acc[t][3] += hv.x * va0.w + hv.y * va1.w;
            }
        }
        #pragma unroll
        for (int t = 0; t < BTF; t++) {
            if (t < nt) {
                float* orow = out + (size_t)toks[t] * DMODEL + v;
                atomicAdd(orow + 0, acc[t][0]);
                atomicAdd(orow + 1, acc[t][1]);
                atomicAdd(orow + 2, acc[t][2]);
                atomicAdd(orow + 3, acc[t][3]);
            }
        }
    }
}

extern "C" void kernel_launch(void* const* d_in, const int* in_sizes, int n_in,
                              void* d_out, int out_size, void* d_ws, size_t ws_size,
                              hipStream_t stream) {
    const float* x      = (const float*)d_in[0];
    const float* esel   = (const float*)d_in[1];
    const float* keys   = (const float*)d_in[2];
    const float* values = (const float*)d_in[3];
    float* out = (float*)d_out;
    int ntok = in_sizes[0] / DMODEL;

    // workspace layout
    const size_t OFF_BASE  = 512;
    const size_t OFF_NT    = 1024;        // int[2]
    const size_t OFF_TILE1 = 2048;
    const size_t OFF_TILE2 = 8 << 10;
    const size_t OFF_HIST  = 16 << 10;
    const size_t OFF_GOFF  = 32 << 10;
    const size_t OFF_SLOT  = 64 << 10;
    const size_t OFF_SELE  = 128 << 10;
    const size_t OFF_SELG  = 192 << 10;
    const size_t OFF_TOK   = 256 << 10;
    const size_t OFF_GATE  = 1ull << 20;
    const size_t OFF_XB    = 2ull << 20;
    const size_t OFF_KT    = 12ull << 20;
    const size_t OFF_VT    = 46ull << 20;
    const size_t OFF_HS    = 80ull << 20;
    const size_t OFF_YS    = 98ull << 20;
    const size_t NEED      = OFF_YS + (size_t)ntok * TOPK * DMODEL * sizeof(float) + (1 << 20);

    int*      counts    = (int*)d_ws;
    int*      ebase     = (int*)((char*)d_ws + OFF_BASE);
    int*      ntiles    = (int*)((char*)d_ws + OFF_NT);
    int*      tiles1    = (int*)((char*)d_ws + OFF_TILE1);
    int*      tiles2    = (int*)((char*)d_ws + OFF_TILE2);
    int*      ghist     = (int*)((char*)d_ws + OFF_HIST);
    int*      goff      = (int*)((char*)d_ws + OFF_GOFF);
    unsigned* slotinfo  = (unsigned*)((char*)d_ws + OFF_SLOT);
    unsigned* sel_e     = (unsigned*)((char*)d_ws + OFF_SELE);
    float*    sel_g     = (float*)((char*)d_ws + OFF_SELG);
    int*      tok_list  = (int*)((char*)d_ws + OFF_TOK);
    float*    gate_list = (float*)((char*)d_ws + OFF_GATE);
    unsigned short* xb  = (unsigned short*)((char*)d_ws + OFF_XB);
    unsigned short* kt  = (unsigned short*)((char*)d_ws + OFF_KT);
    unsigned short* vt  = (unsigned short*)((char*)d_ws + OFF_VT);

    int nsel = ntok * TOPK;
    int rblocks = (ntok + RTB - 1) / RTB;

    if (ws_size >= NEED) {
        unsigned short* hs = (unsigned short*)((char*)d_ws + OFF_HS);
        unsigned short* ys = (unsigned short*)((char*)d_ws + OFF_YS);

        // fused routing + weight-prep (independent work, one launch)
        front_k<<<rblocks + 8192, 256, 0, stream>>>(
            x, esel, keys, values, xb, kt, vt, sel_e, sel_g, ntok, rblocks);

        hist_k<<<NBORD, 256, 0, stream>>>(sel_e, ghist, nsel);
        scan2_k<<<1, 64, 0, stream>>>(ghist, goff, counts, ebase, tiles1, tiles2,
                                      ntiles, NBORD);
        scat_k<<<NBORD, 256, 0, stream>>>(sel_e, sel_g, goff, tok_list, gate_list,
                                          slotinfo, nsel, ntok);

        int maxt1 = (nsel + MT1 - 1) / MT1 + NEXP;
        int maxt2 = (nsel + MT2 - 1) / MT2 + NEXP;
        gemm1_k<<<dim3(maxt1, FDIM / 256), 512, 0, stream>>>(
            xb, kt, counts, ebase, tiles1, ntiles, tok_list, gate_list, hs, ntok);
        gemm2_k<<<dim3(maxt2, DMODEL / 128), 256, 0, stream>>>(
            hs, vt, counts, ebase, tiles2, ntiles, ys);
        combine_k<<<ntok, 256, 0, stream>>>(ys, slotinfo, ebase, out);
    } else {
        hipError_t _e1 = hipMemsetAsync(counts, 0, NEXP * sizeof(int), stream); (void)_e1;
        hipError_t _e2 = hipMemsetAsync(out, 0, (size_t)out_size * sizeof(float), stream); (void)_e2;
        // fallback: routing blocks only (prep branch unreachable at grid=rblocks)
        front_k<<<rblocks, 256, 0, stream>>>(
            x, esel, keys, values, xb, kt, vt, sel_e, sel_g, ntok, rblocks);
        hist_k<<<NBORD, 256, 0, stream>>>(sel_e, ghist, nsel);
        scan2_k<<<1, 64, 0, stream>>>(ghist, goff, counts, ebase, tiles1, tiles2,
                                      ntiles, NBORD);
        scat_k<<<NBORD, 256, 0, stream>>>(sel_e, sel_g, goff, tok_list, gate_list,
                                          slotinfo, nsel, ntok);
        int ntiles2f = (ntok + BTF - 1) / BTF;
        expert_k<<<dim3(ntiles2f, NEXP), 256, 0, stream>>>(
            x, keys, values, counts, tok_list, gate_list, out, ntok);
    }
}

// Round 27
// 162.657 us; speedup vs baseline: 1.1471x; 1.0140x over previous
//
#include <hip/hip_runtime.h>

#define DMODEL 1024
#define NEXP   32
#define FDIM   512
#define TOPK   4

#define MT1   256   // gemm1 token tile
#define MT2   128   // gemm2 token tile
#define BK    64    // k per stage (2 MFMA k-slices)
#define RTB   4     // tokens per routing block (16.5 KB LDS -> high occupancy)
#define NBORD 64    // blocks for hist/scatter phases

using short8 = __attribute__((ext_vector_type(8))) short;
using f32x4  = __attribute__((ext_vector_type(4))) float;

#define AS1 __attribute__((address_space(1)))
#define AS3 __attribute__((address_space(3)))
__device__ __forceinline__ void gload_lds16(const void* g, void* l) {
    __builtin_amdgcn_global_load_lds((const AS1 unsigned int*)g, (AS3 unsigned int*)l, 16, 0, 0);
}

__device__ __forceinline__ unsigned short f2b(float f) {
    unsigned int u = __float_as_uint(f);
    unsigned int r = (u + 0x7FFFu + ((u >> 16) & 1u)) >> 16;   // RNE bf16
    return (unsigned short)r;
}
__device__ __forceinline__ float b2f(unsigned short u) {
    return __uint_as_float((unsigned int)u << 16);
}

// ------- FUSED front: routing blocks + weight-transpose blocks in one launch -------
__global__ __launch_bounds__(256) void front_k(
    const float* __restrict__ x, const float* __restrict__ esel,
    const float* __restrict__ keys, const float* __restrict__ values,
    unsigned short* __restrict__ xb,
    unsigned short* __restrict__ kt, unsigned short* __restrict__ vt,
    unsigned int* __restrict__ sel_e, float* __restrict__ sel_g,
    int ntok, int rblocks)
{
    __shared__ float smem[RTB * DMODEL + RTB * NEXP];   // 16.9 KB (union, >= 16.3 KB tile)
    int bid = blockIdx.x;
    int tid = threadIdx.x;

    if (bid < rblocks) {
        // ---------------- routing body (RTB=4) ----------------
        float (*xs)[DMODEL] = (float(*)[DMODEL])smem;
        float (*gs)[NEXP]   = (float(*)[NEXP])(smem + RTB * DMODEL);
        int tile0 = bid * RTB;

        {
            const float4* src = (const float4*)(x + (size_t)tile0 * DMODEL);
            float4* dst = (float4*)&xs[0][0];
            int navail = min(RTB, ntok - tile0) * (DMODEL / 4);
            for (int i = tid; i < RTB * (DMODEL / 4); i += 256)
                dst[i] = src[i < navail ? i : 0];
        }
        __syncthreads();

        int e = tid >> 3, sub = tid & 7;
        float4 acc0 = {0,0,0,0}, acc1 = {0,0,0,0}, acc2 = {0,0,0,0}, acc3 = {0,0,0,0};
        const float* er = esel + (size_t)e * DMODEL + sub * 4;
        #pragma unroll 4
        for (int j = 0; j < DMODEL / 32; j++) {
            float4 ev = *(const float4*)(er + j * 32);
            int kk = sub * 4 + j * 32;
            float4 x0 = *(const float4*)(&xs[0][kk]);
            float4 x1 = *(const float4*)(&xs[1][kk]);
            float4 x2 = *(const float4*)(&xs[2][kk]);
            float4 x3 = *(const float4*)(&xs[3][kk]);
            acc0.x += ev.x*x0.x; acc0.y += ev.y*x0.y; acc0.z += ev.z*x0.z; acc0.w += ev.w*x0.w;
            acc1.x += ev.x*x1.x; acc1.y += ev.y*x1.y; acc1.z += ev.z*x1.z; acc1.w += ev.w*x1.w;
            acc2.x += ev.x*x2.x; acc2.y += ev.y*x2.y; acc2.z += ev.z*x2.z; acc2.w += ev.w*x2.w;
            acc3.x += ev.x*x3.x; acc3.y += ev.y*x3.y; acc3.z += ev.z*x3.z; acc3.w += ev.w*x3.w;
        }
        {
            float s[RTB] = {
                acc0.x+acc0.y+acc0.z+acc0.w, acc1.x+acc1.y+acc1.z+acc1.w,
                acc2.x+acc2.y+acc2.z+acc2.w, acc3.x+acc3.y+acc3.z+acc3.w };
            #pragma unroll
            for (int t = 0; t < RTB; t++) {
                float v = s[t];
                v += __shfl_xor(v, 1);
                v += __shfl_xor(v, 2);
                v += __shfl_xor(v, 4);
                if (sub == 0) gs[t][e] = 1.f / (1.f + expf(-v));
            }
        }
        __syncthreads();

        {
            int t = tid >> 5, e2 = tid & 31;
            int tok = tile0 + t;
            if (t < RTB && tok < ntok) {
                float v = gs[t][e2];
                #pragma unroll
                for (int r = 0; r < TOPK; r++) {
                    float bv = v; int bi = e2;
                    #pragma unroll
                    for (int sft = 16; sft >= 1; sft >>= 1) {
                        float ov = __shfl_xor(bv, sft, 32);
                        int   oi = __shfl_xor(bi, sft, 32);
                        if (ov > bv || (ov == bv && oi < bi)) { bv = ov; bi = oi; }
                    }
                    if (e2 == bi) v = -1e30f;
                    if (e2 == r) {
                        sel_e[(size_t)tok * TOPK + r] = (unsigned)bi;
                        sel_g[(size_t)tok * TOPK + r] = bv;
                    }
                }
            }
        }

        {
            int navail = min(RTB, ntok - tile0) * (DMODEL / 4);
            ushort4* dst = (ushort4*)(xb + (size_t)tile0 * DMODEL);
            const float4* srcl = (const float4*)&xs[0][0];
            for (int i = tid; i < navail; i += 256) {
                float4 v = srcl[i];
                ushort4 o;
                o.x = f2b(v.x); o.y = f2b(v.y); o.z = f2b(v.z); o.w = f2b(v.w);
                dst[i] = o;
            }
        }
    } else {
        // ---------------- prep body (vectorized transpose) ----------------
        float (*tile)[65] = (float(*)[65])smem;     // 16.3 KB of the union
        int pid = bid - rblocks;                    // 0..8191
        int e     = pid >> 8;                       // 0..31
        int rem   = pid & 255;
        int which = rem >> 7;                       // 0: keys, 1: values
        int flat  = rem & 127;                      // 0..127
        int R = which ? FDIM : DMODEL;
        int C = which ? DMODEL : FDIM;
        const float* src = which ? values : keys;
        unsigned short* dst = which ? vt : kt;
        int ctiles = C >> 6;
        int cx = flat % ctiles, ry = flat / ctiles;
        int r0 = ry * 64, c0 = cx * 64;
        const float* s = src + (size_t)e * R * C;
        unsigned short* d = dst + (size_t)e * R * C;

        #pragma unroll
        for (int it = 0; it < 4; it++) {
            int lin = it * 1024 + tid * 4;
            int rr = lin >> 6, cc = lin & 63;
            float4 v = *(const float4*)(s + (size_t)(r0 + rr) * C + c0 + cc);
            tile[rr][cc]     = v.x;
            tile[rr][cc + 1] = v.y;
            tile[rr][cc + 2] = v.z;
            tile[rr][cc + 3] = v.w;
        }
        __syncthreads();
        #pragma unroll
        for (int it = 0; it < 4; it++) {
            int lin = it * 1024 + tid * 4;
            int wr = lin >> 6, wc = lin & 63;
            ushort4 o;
            o.x = f2b(tile[wc][wr]);
            o.y = f2b(tile[wc + 1][wr]);
            o.z = f2b(tile[wc + 2][wr]);
            o.w = f2b(tile[wc + 3][wr]);
            *(ushort4*)(d + (size_t)(c0 + wr) * R + r0 + wc) = o;
        }
    }
}

// ------- phase B1: per-block expert histogram -------
__global__ __launch_bounds__(256) void hist_k(
    const unsigned int* __restrict__ sel_e, int* __restrict__ ghist, int nsel)
{
    __shared__ int h[NEXP];
    int tid = threadIdx.x;
    if (tid < NEXP) h[tid] = 0;
    __syncthreads();
    int chunk = (nsel + gridDim.x - 1) / gridDim.x;
    int i0 = blockIdx.x * chunk, i1 = min(i0 + chunk, nsel);
    for (int i = i0 + tid; i < i1; i += 256)
        atomicAdd(&h[sel_e[i]], 1);
    __syncthreads();
    if (tid < NEXP) ghist[blockIdx.x * NEXP + tid] = h[tid];
}

// ------- phase B2: prefix + base + BOTH tile lists -------
__global__ __launch_bounds__(64) void scan2_k(
    const int* __restrict__ ghist, int* __restrict__ goff,
    int* __restrict__ counts, int* __restrict__ base,
    int* __restrict__ tiles1, int* __restrict__ tiles2,
    int* __restrict__ ntiles, int nb)
{
    int e = threadIdx.x;
    if (e < NEXP) {
        int s = 0;
        for (int b = 0; b < nb; b++) {
            goff[b * NEXP + e] = s;
            s += ghist[b * NEXP + e];
        }
        counts[e] = s;
    }
    __syncthreads();
    if (e == 0) {
        int s = 0, nt1 = 0, nt2 = 0;
        for (int e2 = 0; e2 < NEXP; e2++) {
            base[e2] = s;
            int c = counts[e2];
            for (int t0 = 0; t0 < c; t0 += MT1) tiles1[nt1++] = (e2 << 8) | (t0 / MT1);
            for (int t0 = 0; t0 < c; t0 += MT2) tiles2[nt2++] = (e2 << 8) | (t0 / MT2);
            s += c;
        }
        ntiles[0] = nt1;
        ntiles[1] = nt2;
    }
}

// ------- phase B3: scatter into lists -------
__global__ __launch_bounds__(256) void scat_k(
    const unsigned int* __restrict__ sel_e, const float* __restrict__ sel_g,
    const int* __restrict__ goff,
    int* __restrict__ tok_list, float* __restrict__ gate_list,
    unsigned int* __restrict__ slotinfo, int nsel, int ntok)
{
    __shared__ int c[NEXP];
    int tid = threadIdx.x;
    if (tid < NEXP) c[tid] = goff[blockIdx.x * NEXP + tid];
    __syncthreads();
    int chunk = (nsel + gridDim.x - 1) / gridDim.x;
    int i0 = blockIdx.x * chunk, i1 = min(i0 + chunk, nsel);
    for (int i = i0 + tid; i < i1; i += 256) {
        unsigned int e = sel_e[i];
        float g = sel_g[i];
        int pos = atomicAdd(&c[e], 1);
        tok_list [(size_t)e * ntok + pos] = i >> 2;
        gate_list[(size_t)e * ntok + pos] = g;
        slotinfo[i] = (e << 16) | (unsigned)pos;
    }
}

// ---- GEMM1: hs = relu(x . K_e)*gate  (256x256, 8 waves, counted-vmcnt dbuf) ----
__global__ __launch_bounds__(512, 2) void gemm1_k(
    const unsigned short* __restrict__ xb,
    const unsigned short* __restrict__ kt,   // [E][512 f][1024 d]
    const int* __restrict__ counts, const int* __restrict__ base,
    const int* __restrict__ tiles, const int* __restrict__ ntiles,
    const int* __restrict__ tok_list, const float* __restrict__ gate_list,
    unsigned short* __restrict__ hs, int ntok)
{
    int ti = blockIdx.x;
    if (ti >= ntiles[0]) return;
    int code = tiles[ti];
    int e = code >> 8, t0 = (code & 255) * MT1;
    int cnt  = counts[e];
    int f0   = blockIdx.y * 256;             // FDIM/256 = 2 tiles
    int live = min(MT1, cnt - t0);

    __shared__ unsigned short Xs[2][MT1 * BK];   // 2 x 32 KB
    __shared__ unsigned short Ks[2][256 * BK];   // 2 x 32 KB
    __shared__ int   toks[MT1];
    __shared__ float gts[MT1];

    int tid = threadIdx.x, lane = tid & 63, wid = tid >> 6;   // 8 waves
    int wr = wid >> 2, wc = wid & 3;                          // 2M x 4N
    int lr = lane & 15, lg = lane >> 4;

    if (tid < MT1) {
        bool lv = tid < live;
        toks[tid] = lv ? tok_list [(size_t)e * ntok + t0 + tid] : 0;
        gts[tid]  = lv ? gate_list[(size_t)e * ntok + t0 + tid] : 0.f;
    }
    __syncthreads();

    int lrow = lane >> 3;
    int scol = ((lane & 7) ^ lrow) * 8;          // pre-swizzled ushort col
    const unsigned short* ke = kt + (size_t)e * FDIM * DMODEL + (size_t)f0 * DMODEL;
    const unsigned short* sx[4];
    const unsigned short* sk[4];
    int dofs[4];
    #pragma unroll
    for (int j = 0; j < 4; j++) {
        int ch = 4 * wid + j;
        int row = ch * 8 + lrow;
        sx[j] = xb + (size_t)toks[row] * DMODEL + scol;
        sk[j] = ke + (size_t)row * DMODEL + scol;
        dofs[j] = ch * 512;
    }

    f32x4 acc[8][4];
    #pragma unroll
    for (int m = 0; m < 8; m++)
        #pragma unroll
        for (int n = 0; n < 4; n++)
            acc[m][n] = (f32x4){0.f, 0.f, 0.f, 0.f};

    #pragma unroll
    for (int j = 0; j < 4; j++) {
        gload_lds16(sx[j], &Xs[0][dofs[j]]);
        gload_lds16(sk[j], &Ks[0][dofs[j]]);
    }

    int cur = 0;
    const int NKT = DMODEL / BK;           // 16
    for (int t = 0; t < NKT; t++) {
        bool more = (t + 1) < NKT;
        if (more) {
            int k1 = (t + 1) * BK;
            #pragma unroll
            for (int j = 0; j < 4; j++) {
                gload_lds16(sx[j] + k1, &Xs[cur ^ 1][dofs[j]]);
                gload_lds16(sk[j] + k1, &Ks[cur ^ 1][dofs[j]]);
            }
            asm volatile("s_waitcnt vmcnt(8)" ::: "memory");
        } else {
            asm volatile("s_waitcnt vmcnt(0)" ::: "memory");
        }
        __builtin_amdgcn_s_barrier();
        __builtin_amdgcn_sched_barrier(0);
        const unsigned short* Xc = Xs[cur];
        const unsigned short* Kc = Ks[cur];
        #pragma unroll
        for (int ks = 0; ks < 2; ks++) {
            short8 a[8];
            #pragma unroll
            for (int m = 0; m < 8; m++) {
                int row = wr * 128 + m * 16 + lr;
                a[m] = *(const short8*)(Xc + row * BK + (((ks * 4 + lg) ^ (lr & 7)) * 8));
            }
            #pragma unroll
            for (int n = 0; n < 4; n++) {
                int row = wc * 64 + n * 16 + lr;
                short8 b = *(const short8*)(Kc + row * BK + (((ks * 4 + lg) ^ (lr & 7)) * 8));
                #pragma unroll
                for (int m = 0; m < 8; m++)
                    acc[m][n] = __builtin_amdgcn_mfma_f32_16x16x32_bf16(a[m], b, acc[m][n], 0, 0, 0);
            }
        }
        __builtin_amdgcn_sched_barrier(0);
        asm volatile("s_waitcnt lgkmcnt(0)" ::: "memory");
        __builtin_amdgcn_s_barrier();
        cur ^= 1;
    }

    int hb = base[e] + t0;
    #pragma unroll
    for (int m = 0; m < 8; m++) {
        #pragma unroll
        for (int n = 0; n < 4; n++) {
            int col = f0 + wc * 64 + n * 16 + lr;
            #pragma unroll
            for (int r = 0; r < 4; r++) {
                int row = wr * 128 + m * 16 + lg * 4 + r;
                if (row < live)
                    hs[(size_t)(hb + row) * FDIM + col] = f2b(fmaxf(acc[m][n][r], 0.f) * gts[row]);
            }
        }
    }
}

// ---- GEMM2: ys(bf16) = hs . V_e  (128x128, 4 waves, counted-vmcnt dbuf) ----
__global__ __launch_bounds__(256) void gemm2_k(
    const unsigned short* __restrict__ hs,
    const unsigned short* __restrict__ vt,   // [E][1024 v][512 f]
    const int* __restrict__ counts, const int* __restrict__ base,
    const int* __restrict__ tiles2, const int* __restrict__ ntiles,
    unsigned short* __restrict__ ys)
{
    int ti = blockIdx.x;
    if (ti >= ntiles[1]) return;
    int code = tiles2[ti];
    int e = code >> 8, t0 = (code & 255) * MT2;
    int cnt  = counts[e];
    int v0   = blockIdx.y * 128;             // DMODEL/128 = 8 tiles
    int live = min(MT2, cnt - t0);
    int hb   = base[e] + t0;

    __shared__ unsigned short Hs[2][MT2 * BK];   // 2 x 16 KB
    __shared__ unsigned short Vs[2][128 * BK];   // 2 x 16 KB

    int tid = threadIdx.x, lane = tid & 63, w = tid >> 6;
    int lr = lane & 15, lg = lane >> 4;

    int lrow = lane >> 3;
    int scol = ((lane & 7) ^ lrow) * 8;
    const unsigned short* he = hs + (size_t)hb * FDIM;
    const unsigned short* ve = vt + (size_t)e * DMODEL * FDIM + (size_t)v0 * FDIM;
    const unsigned short* sh[4];
    const unsigned short* sv[4];
    int dofs[4];
    #pragma unroll
    for (int j = 0; j < 4; j++) {
        int ch = 4 * w + j;
        int row = ch * 8 + lrow;
        sh[j] = he + (size_t)row * FDIM + scol;      // may over-read slack rows
        sv[j] = ve + (size_t)row * FDIM + scol;
        dofs[j] = ch * 512;
    }

    f32x4 acc[8][2];
    #pragma unroll
    for (int m = 0; m < 8; m++)
        #pragma unroll
        for (int n = 0; n < 2; n++)
            acc[m][n] = (f32x4){0.f, 0.f, 0.f, 0.f};

    #pragma unroll
    for (int j = 0; j < 4; j++) {
        gload_lds16(sh[j], &Hs[0][dofs[j]]);
        gload_lds16(sv[j], &Vs[0][dofs[j]]);
    }

    int cur = 0;
    const int NKT = FDIM / BK;             // 8
    for (int t = 0; t < NKT; t++) {
        bool more = (t + 1) < NKT;
        if (more) {
            int k1 = (t + 1) * BK;
            #pragma unroll
            for (int j = 0; j < 4; j++) {
                gload_lds16(sh[j] + k1, &Hs[cur ^ 1][dofs[j]]);
                gload_lds16(sv[j] + k1, &Vs[cur ^ 1][dofs[j]]);
            }
            asm volatile("s_waitcnt vmcnt(8)" ::: "memory");
        } else {
            asm volatile("s_waitcnt vmcnt(0)" ::: "memory");
        }
        __builtin_amdgcn_s_barrier();
        __builtin_amdgcn_sched_barrier(0);
        const unsigned short* Hc = Hs[cur];
        const unsigned short* Vc = Vs[cur];
        #pragma unroll
        for (int ks = 0; ks < 2; ks++) {
            short8 a[8];
            #pragma unroll
            for (int m = 0; m < 8; m++) {
                int row = m * 16 + lr;
                a[m] = *(const short8*)(Hc + row * BK + (((ks * 4 + lg) ^ (lr & 7)) * 8));
            }
            #pragma unroll
            for (int n = 0; n < 2; n++) {
                int row = w * 32 + n * 16 + lr;
                short8 b = *(const short8*)(Vc + row * BK + (((ks * 4 + lg) ^ (lr & 7)) * 8));
                #pragma unroll
                for (int m = 0; m < 8; m++)
                    acc[m][n] = __builtin_amdgcn_mfma_f32_16x16x32_bf16(a[m], b, acc[m][n], 0, 0, 0);
            }
        }
        __builtin_amdgcn_sched_barrier(0);
        asm volatile("s_waitcnt lgkmcnt(0)" ::: "memory");
        __builtin_amdgcn_s_barrier();
        cur ^= 1;
    }

    #pragma unroll
    for (int m = 0; m < 8; m++) {
        #pragma unroll
        for (int n = 0; n < 2; n++) {
            int col = v0 + w * 32 + n * 16 + lr;
            #pragma unroll
            for (int r = 0; r < 4; r++) {
                int row = m * 16 + lg * 4 + r;
                if (row < live)
                    ys[(size_t)(hb + row) * DMODEL + col] = f2b(acc[m][n][r]);
            }
        }
    }
}

// ------- combine -------
__global__ __launch_bounds__(256) void combine_k(
    const unsigned short* __restrict__ ys, const unsigned int* __restrict__ slotinfo,
    const int* __restrict__ base, float* __restrict__ out)
{
    int tok = blockIdx.x;
    unsigned int s0 = slotinfo[(size_t)tok * TOPK + 0];
    unsigned int s1 = slotinfo[(size_t)tok * TOPK + 1];
    unsigned int s2 = slotinfo[(size_t)tok * TOPK + 2];
    unsigned int s3 = slotinfo[(size_t)tok * TOPK + 3];
    const ushort4* y0 = (const ushort4*)(ys + (size_t)(base[s0 >> 16] + (s0 & 0xFFFF)) * DMODEL);
    const ushort4* y1 = (const ushort4*)(ys + (size_t)(base[s1 >> 16] + (s1 & 0xFFFF)) * DMODEL);
    const ushort4* y2 = (const ushort4*)(ys + (size_t)(base[s2 >> 16] + (s2 & 0xFFFF)) * DMODEL);
    const ushort4* y3 = (const ushort4*)(ys + (size_t)(base[s3 >> 16] + (s3 & 0xFFFF)) * DMODEL);
    int i = threadIdx.x;
    ushort4 a = y0[i], b = y1[i], c = y2[i], d = y3[i];
    float4 o;
    o.x = b2f(a.x) + b2f(b.x) + b2f(c.x) + b2f(d.x);
    o.y = b2f(a.y) + b2f(b.y) + b2f(c.y) + b2f(d.y);
    o.z = b2f(a.z) + b2f(b.z) + b2f(c.z) + b2f(d.z);
    o.w = b2f(a.w) + b2f(b.w) + b2f(c.w) + b2f(d.w);
    ((float4*)(out + (size_t)tok * DMODEL))[i] = o;
}

// ---------------- fp32 fallback ----------------
#define BTF 16
__global__ __launch_bounds__(256) void expert_k(
    const float* __restrict__ x, const float* __restrict__ keys,
    const float* __restrict__ values, const int* __restrict__ counts,
    const int* __restrict__ tok_list, const float* __restrict__ gate_list,
    float* __restrict__ out, int ntok)
{
    int e   = blockIdx.y;
    int cnt = counts[e];
    int t0  = blockIdx.x * BTF;
    if (t0 >= cnt) return;
    int nt = (cnt - t0 < BTF) ? (cnt - t0) : BTF;

    __shared__ float xs[BTF][DMODEL];
    __shared__ float hsl[BTF][FDIM];
    __shared__ int   toks[BTF];
    __shared__ float gts[BTF];

    if (threadIdx.x < BTF) {
        int t = threadIdx.x;
        bool live = (t < nt);
        toks[t] = live ? tok_list [(size_t)e * ntok + t0 + t] : 0;
        gts[t]  = live ? gate_list[(size_t)e * ntok + t0 + t] : 0.f;
    }
    __syncthreads();
    for (int i = threadIdx.x; i < BTF * (DMODEL / 4); i += 256) {
        int r = i >> 8, c = i & 255;
        ((float4*)xs[r])[c] = ((const float4*)(x + (size_t)toks[r] * DMODEL))[c];
    }
    __syncthreads();

    {
        int f = threadIdx.x * 2;
        float acc0[BTF], acc1[BTF];
        #pragma unroll
        for (int t = 0; t < BTF; t++) { acc0[t] = 0.f; acc1[t] = 0.f; }
        const float* kp = keys + (size_t)e * DMODEL * FDIM + f;
        for (int k = 0; k < DMODEL; k += 4) {
            const float* kr = kp + (size_t)k * FDIM;
            float2 kv0 = *(const float2*)(kr);
            float2 kv1 = *(const float2*)(kr + FDIM);
            float2 kv2 = *(const float2*)(kr + 2 * FDIM);
            float2 kv3 = *(const float2*)(kr + 3 * FDIM);
            #pragma unroll
            for (int t = 0; t < BTF; t++) {
                float4 xv = *(const float4*)(&xs[t][k]);
                acc0[t] += xv.x * kv0.x + xv.y * kv1.x + xv.z * kv2.x + xv.w * kv3.x;
                acc1[t] += xv.x * kv0.y + xv.y * kv1.y + xv.z * kv2.y + xv.w * kv3.y;
            }
        }
        #pragma unroll
        for (int t = 0; t < BTF; t++) {
            float g = gts[t];
            hsl[t][f]     = fmaxf(acc0[t], 0.f) * g;
            hsl[t][f + 1] = fmaxf(acc1[t], 0.f) * g;
        }
    }
    __syncthreads();

    {
        int v = threadIdx.x * 4;
        float acc[BTF][4];
        #pragma unroll
        for (int t = 0; t < BTF; t++) { acc[t][0]=0.f; acc[t][1]=0.f; acc[t][2]=0.f; acc[t][3]=0.f; }
        const float* vp = values + (size_t)e * FDIM * DMODEL + v;
        for (int k = 0; k < FDIM; k += 2) {
            float4 va0 = *(const float4*)(vp + (size_t)k * DMODEL);
            float4 va1 = *(const float4*)(vp + (size_t)(k + 1) * DMODEL);
            #pragma unroll
            for (int t = 0; t < BTF; t++) {
                float2 hv = *(const float2*)(&hsl[t][k]);
                acc[t][0] += hv.x * va0.x + hv.y * va1.x;
                acc[t][1] += hv.x * va0.y + hv.y * va1.y;
                acc[t][2] += hv.x * va0.z + hv.y * va1.z;
                acc[t][3] += hv.x * va0.w + hv.y * va1.w;
            }
        }
        #pragma unroll
        for (int t = 0; t < BTF; t++) {
            if (t < nt) {
                float* orow = out + (size_t)toks[t] * DMODEL + v;
                atomicAdd(orow + 0, acc[t][0]);
                atomicAdd(orow + 1, acc[t][1]);
                atomicAdd(orow + 2, acc[t][2]);
                atomicAdd(orow + 3, acc[t][3]);
            }
        }
    }
}

extern "C" void kernel_launch(void* const* d_in, const int* in_sizes, int n_in,
                              void* d_out, int out_size, void* d_ws, size_t ws_size,
                              hipStream_t stream) {
    const float* x      = (const float*)d_in[0];
    const float* esel   = (const float*)d_in[1];
    const float* keys   = (const float*)d_in[2];
    const float* values = (const float*)d_in[3];
    float* out = (float*)d_out;
    int ntok = in_sizes[0] / DMODEL;

    // workspace layout
    const size_t OFF_BASE  = 512;
    const size_t OFF_NT    = 1024;        // int[2]
    const size_t OFF_TILE1 = 2048;
    const size_t OFF_TILE2 = 8 << 10;
    const size_t OFF_HIST  = 16 << 10;
    const size_t OFF_GOFF  = 32 << 10;
    const size_t OFF_SLOT  = 64 << 10;
    const size_t OFF_SELE  = 128 << 10;
    const size_t OFF_SELG  = 192 << 10;
    const size_t OFF_TOK   = 256 << 10;
    const size_t OFF_GATE  = 1ull << 20;
    const size_t OFF_XB    = 2ull << 20;
    const size_t OFF_KT    = 12ull << 20;
    const size_t OFF_VT    = 46ull << 20;
    const size_t OFF_HS    = 80ull << 20;
    const size_t OFF_YS    = 98ull << 20;
    const size_t NEED      = OFF_YS + (size_t)ntok * TOPK * DMODEL * sizeof(float) + (1 << 20);

    int*      counts    = (int*)d_ws;
    int*      ebase     = (int*)((char*)d_ws + OFF_BASE);
    int*      ntiles    = (int*)((char*)d_ws + OFF_NT);
    int*      tiles1    = (int*)((char*)d_ws + OFF_TILE1);
    int*      tiles2    = (int*)((char*)d_ws + OFF_TILE2);
    int*      ghist     = (int*)((char*)d_ws + OFF_HIST);
    int*      goff      = (int*)((char*)d_ws + OFF_GOFF);
    unsigned* slotinfo  = (unsigned*)((char*)d_ws + OFF_SLOT);
    unsigned* sel_e     = (unsigned*)((char*)d_ws + OFF_SELE);
    float*    sel_g     = (float*)((char*)d_ws + OFF_SELG);
    int*      tok_list  = (int*)((char*)d_ws + OFF_TOK);
    float*    gate_list = (float*)((char*)d_ws + OFF_GATE);
    unsigned short* xb  = (unsigned short*)((char*)d_ws + OFF_XB);
    unsigned short* kt  = (unsigned short*)((char*)d_ws + OFF_KT);
    unsigned short* vt  = (unsigned short*)((char*)d_ws + OFF_VT);

    int nsel = ntok * TOPK;
    int rblocks = (ntok + RTB - 1) / RTB;

    if (ws_size >= NEED) {
        unsigned short* hs = (unsigned short*)((char*)d_ws + OFF_HS);
        unsigned short* ys = (unsigned short*)((char*)d_ws + OFF_YS);

        // fused routing + weight-prep (independent work, one launch)
        front_k<<<rblocks + 8192, 256, 0, stream>>>(
            x, esel, keys, values, xb, kt, vt, sel_e, sel_g, ntok, rblocks);

        hist_k<<<NBORD, 256, 0, stream>>>(sel_e, ghist, nsel);
        scan2_k<<<1, 64, 0, stream>>>(ghist, goff, counts, ebase, tiles1, tiles2,
                                      ntiles, NBORD);
        scat_k<<<NBORD, 256, 0, stream>>>(sel_e, sel_g, goff, tok_list, gate_list,
                                          slotinfo, nsel, ntok);

        int maxt1 = (nsel + MT1 - 1) / MT1 + NEXP;
        int maxt2 = (nsel + MT2 - 1) / MT2 + NEXP;
        gemm1_k<<<dim3(maxt1, FDIM / 256), 512, 0, stream>>>(
            xb, kt, counts, ebase, tiles1, ntiles, tok_list, gate_list, hs, ntok);
        gemm2_k<<<dim3(maxt2, DMODEL / 128), 256, 0, stream>>>(
            hs, vt, counts, ebase, tiles2, ntiles, ys);
        combine_k<<<ntok, 256, 0, stream>>>(ys, slotinfo, ebase, out);
    } else {
        hipError_t _e1 = hipMemsetAsync(counts, 0, NEXP * sizeof(int), stream); (void)_e1;
        hipError_t _e2 = hipMemsetAsync(out, 0, (size_t)out_size * sizeof(float), stream); (void)_e2;
        // fallback: routing blocks only (prep branch unreachable at grid=rblocks)
        front_k<<<rblocks, 256, 0, stream>>>(
            x, esel, keys, values, xb, kt, vt, sel_e, sel_g, ntok, rblocks);
        hist_k<<<NBORD, 256, 0, stream>>>(sel_e, ghist, nsel);
        scan2_k<<<1, 64, 0, stream>>>(ghist, goff, counts, ebase, tiles1, tiles2,
                                      ntiles, NBORD);
        scat_k<<<NBORD, 256, 0, stream>>>(sel_e, sel_g, goff, tok_list, gate_list,
                                          slotinfo, nsel, ntok);
        int ntiles2f = (ntok + BTF - 1) / BTF;
        expert_k<<<dim3(ntiles2f, NEXP), 256, 0, stream>>>(
            x, keys, values, counts, tok_list, gate_list, out, ntok);
    }
}